// Round 1
// baseline (8833.179 us; speedup 1.0000x reference)
//
#include <hip/hip_runtime.h>
#include <stdint.h>

#define TT 2048
#define BB 64
#define HH 256

// ws float-word layout
#define WIHT_OFF 0          // W_ih^T : 256 tokens x 1024 gate-rows
#define BIAS_OFF 262144     // b_ih + b_hh : 1024
#define HBUF_OFF 263168     // packed h exchange: u64[2][64][256] = 65536 floats
#define XMAP_OFF 328704     // 256 u32: per-WG published XCC id (0x100 | id)
#define WS_TOT   328960

#define LOGITS   33554432   // 64*2048*256

// ---------------- K1: prep (transpose W_ih, fuse biases, zero exch+xmap) ------
__global__ __launch_bounds__(256, 1) void k_prep(const float* __restrict__ W_ih,
                                                 const float* __restrict__ b_ih,
                                                 const float* __restrict__ b_hh,
                                                 float* ws_f) {
    int idx = blockIdx.x * 256 + threadIdx.x;
    if (idx < 262144) {
        int v = idx >> 10, r = idx & 1023;
        ws_f[WIHT_OFF + idx] = W_ih[r * 256 + v];
    } else if (idx < 263168) {
        int r = idx - 262144;
        ws_f[idx] = b_ih[r] + b_hh[r];
    } else if (idx < WS_TOT) {
        ws_f[idx] = 0.0f;   // exchange slots (epoch=0,val=0) + xcc map = 0
    }
}

__device__ __forceinline__ float tanh_f(float x) {
    float e = __expf(2.0f * x);
    return 1.0f - 2.0f / (e + 1.0f);   // +-inf-safe: -> 1 / -1
}

// fast-path read: bypass L1, served from the (shared, same-XCD) L2.
__device__ __forceinline__ unsigned long long ld_l2(const unsigned long long* p) {
    unsigned long long v;
    asm volatile("global_load_dwordx2 %0, %1, off sc0\n\ts_waitcnt vmcnt(0)"
                 : "=v"(v) : "v"(p) : "memory");
    return v;
}

// ---------------- K2: persistent LSTM recurrence + fused FC -------------------
// 256 WGs x 256 threads; WG (b,q) owns hidden units [q*64,q*64+64) of batch b.
// QUAD layout: thread = (unit uj = tid>>2, gate s = tid&3). The 4 gates of a
// unit live in 4 adjacent lanes of ONE wave -> gate combine is 4 intra-wave
// shuffles; c,h computed redundantly per quad. ONE barrier per step (hin/hloc
// double-buffered). FC fused: thread (uj,s) accumulates logit v=q*64+uj over
// k-quarter s, quad shfl_xor reduce, lane s==0 streams it out (nt).
__global__ __launch_bounds__(256, 1) void k_lstm(const int* __restrict__ x,
                                                 const float* __restrict__ W_hh,
                                                 const float* __restrict__ wsro,
                                                 unsigned long long* __restrict__ hbuf,
                                                 unsigned* __restrict__ xmap,
                                                 const float* __restrict__ fc_W,
                                                 const float* __restrict__ fc_b,
                                                 float* __restrict__ out) {
    const int tid = threadIdx.x;
    const int bid = blockIdx.x;
    const int xcd  = bid & 7;
    const int slot = bid >> 3;
    const int b = xcd + 8 * (slot >> 2);
    const int q = slot & 3;
    const int w  = tid >> 6;            // wave id (polls quarter w for w<3)
    const int u  = tid & 63;            // lane in wave
    const int s  = tid & 3;             // gate 0=i 1=f 2=g 3=o ; FC k-quarter
    const int uj = tid >> 2;            // unit within WG quarter [0,64)
    const int jg = q * 64 + uj;         // global hidden index
    const int r  = s * 256 + jg;        // gate row in [0,1024)

    __shared__ alignas(16) float hin[2][192];   // remote quarters, rotated order
    __shared__ alignas(16) float hloc[2][64];   // own quarter's h
    __shared__ int xs[4];

    // ---- one-time: W_hh row r -> regs, column-rotated (own quarter last) ----
    float4 w4[64];
#pragma unroll
    for (int i = 0; i < 64; ++i) {
        int cb = (i < 48) ? ((q + 1 + (i >> 4)) & 3) : q;
        int wi = (i < 48) ? (i & 15) : (i - 48);
        w4[i] = *(const float4*)(W_hh + (size_t)r * 256 + cb * 64 + wi * 4);
    }
    // ---- one-time: FC slice -> regs: row jg, k-chunk [s*64, s*64+64) ----
    float4 fw[16];
#pragma unroll
    for (int i = 0; i < 16; ++i)
        fw[i] = *(const float4*)(fc_W + (size_t)jg * 256 + s * 64 + i * 4);
    const float bias_r = wsro[BIAS_OFF + r];
    const float fcb = fc_b[jg];
    const int* xrow = x + b * TT;

    // ---- one-time: XCC handshake (ground truth; failure -> slow mode) ----
    int myxcc = 0;
    asm volatile("s_getreg_b32 %0, hwreg(HW_REG_XCC_ID)" : "=s"(myxcc));
    if (tid == 0)
        __hip_atomic_store(&xmap[bid], 0x100u | (unsigned)myxcc,
                           __ATOMIC_RELAXED, __HIP_MEMORY_SCOPE_AGENT);
    if (tid < 4) {
        int pb = (b & 7) + 8 * ((b >> 3) * 4 + tid);
        unsigned v; int g = 0;
        do {
            v = __hip_atomic_load(&xmap[pb], __ATOMIC_RELAXED, __HIP_MEMORY_SCOPE_AGENT);
        } while (!(v & 0x100u) && ++g < (1 << 20));
        xs[tid] = (v & 0x100u) ? (int)(v & 0xffu) : -1 - tid;  // timeout -> mismatch
    }
    if (tid < 64) hloc[0][tid] = 0.0f;  // h(0) = 0
    float c_state = 0.0f;               // per quad (redundant x4, identical)
    __syncthreads();
    bool fastm = (xs[0] == xs[1]) & (xs[1] == xs[2]) & (xs[2] == xs[3]);

    // poll role: waves 0..2 poll remote quarter cq=(q+1+w)&3 into hin slot w
    const bool pollme = (tid < 192);
    const int cq = (q + 1 + w) & 3;

    // prefetch x_proj for t=0
    float xw_cur = wsro[WIHT_OFF + xrow[0] * 1024 + r] + bias_r;
    float hval = 0.0f;

    for (int t = 0; t < TT; ++t) {
        // issue next step's gather NOW (token path is recurrence-independent;
        // a full step of latency hiding even on an HBM miss)
        const int tn = (t + 1 < TT) ? t + 1 : t;
        const float xw_next_raw = wsro[WIHT_OFF + xrow[tn] * 1024 + r];

        // poll remote quarters of h(t) (packed epoch|value), write rotated slot
        if (pollme) {
            const unsigned long long* src =
                hbuf + (size_t)(t & 1) * (BB * HH) + b * HH + cq * 64 + u;
            const unsigned ut = (unsigned)t;
            unsigned long long v = 0;
            if (fastm) {                 // shared-L2 poll, guarded
                int g = 0;
                do { v = ld_l2(src); } while ((unsigned)(v >> 32) != ut && ++g < 6000);
                if ((unsigned)(v >> 32) != ut) fastm = false;  // sticky fallback
            }
            if (!fastm) {                // proven device-scope path
                int g = 0;
                do {
                    v = __hip_atomic_load(src, __ATOMIC_RELAXED, __HIP_MEMORY_SCOPE_AGENT);
                } while ((unsigned)(v >> 32) != ut && ++g < (1 << 21));
            }
            hin[t & 1][w * 64 + u] = __uint_as_float((unsigned)v);
        }
        __syncthreads();                 // the ONLY barrier per step

        const float4* hl4 = (const float4*)hloc[t & 1];
        const float4* hn4 = (const float4*)hin[t & 1];
        float a0 = 0.f, a1 = 0.f, a2 = 0.f, a3 = 0.f;
#pragma unroll
        for (int i = 0; i < 16; ++i) {
            float4 hh = hl4[i];
            a0 += w4[48 + i].x * hh.x;
            a1 += w4[48 + i].y * hh.y;
            a2 += w4[48 + i].z * hh.z;
            a3 += w4[48 + i].w * hh.w;
        }
#pragma unroll
        for (int i = 0; i < 48; ++i) {
            float4 hh = hn4[i];
            a0 += w4[i].x * hh.x;
            a1 += w4[i].y * hh.y;
            a2 += w4[i].z * hh.z;
            a3 += w4[i].w * hh.w;
        }
        float gate = xw_cur + ((a0 + a1) + (a2 + a3));
        // unified branch-free activation: B=2 -> tanh, B=1 -> sigmoid
        const float B2 = (s == 2) ? 2.0f : 1.0f;
        float ex = __expf(B2 * gate);
        float act = 1.0f - B2 / (ex + 1.0f);

        // quad gather of the 4 gates (intra-wave, no barrier)
        const int qb = u & ~3;
        float ig = __shfl(act, qb + 0);
        float fg = __shfl(act, qb + 1);
        float gg = __shfl(act, qb + 2);
        float og = __shfl(act, qb + 3);
        c_state = fg * c_state + ig * gg;
        hval = og * tanh_f(c_state);

        // critical-path store first: device scope (feeds peers' L2 polls)
        if (s == 0) {
            unsigned long long pv =
                ((unsigned long long)(unsigned)(t + 1) << 32) |
                (unsigned long long)__float_as_uint(hval);
            __hip_atomic_store(hbuf + (size_t)((t + 1) & 1) * (BB * HH) + b * HH + jg,
                               pv, __ATOMIC_RELAXED, __HIP_MEMORY_SCOPE_AGENT);
            hloc[(t + 1) & 1][uj] = hval;
        }

        // fused FC for row t-1 (h(t) is assembled in LDS) — runs in the slack
        // while peers poll our h(t+1)
        if (t > 0) {
            const float4* hs = (s == q) ? hl4 : (hn4 + ((s - q + 3) & 3) * 16);
            float b0 = 0.f, b1 = 0.f, b2 = 0.f, b3 = 0.f;
#pragma unroll
            for (int k = 0; k < 16; ++k) {
                float4 hh = hs[k];
                b0 += fw[k].x * hh.x;
                b1 += fw[k].y * hh.y;
                b2 += fw[k].z * hh.z;
                b3 += fw[k].w * hh.w;
            }
            float lg = (b0 + b1) + (b2 + b3);
            lg += __shfl_xor(lg, 1);
            lg += __shfl_xor(lg, 2);
            if (s == 0)
                __builtin_nontemporal_store(lg + fcb,
                    out + ((size_t)(b * TT + (t - 1)) << 8) + jg);
        }
        xw_cur = xw_next_raw + bias_r;
    }

    // h_n, c_n
    if (s == 0) {
        __builtin_nontemporal_store(hval,    out + LOGITS + b * HH + jg);
        __builtin_nontemporal_store(c_state, out + LOGITS + BB * HH + b * HH + jg);
    }

    // final logits row TT-1 from h(TT): epoch TT lives in buffer 0
    if (pollme) {
        const unsigned long long* src = hbuf + b * HH + cq * 64 + u;
        const unsigned ut = (unsigned)TT;
        unsigned long long v = 0;
        if (fastm) {
            int g = 0;
            do { v = ld_l2(src); } while ((unsigned)(v >> 32) != ut && ++g < 6000);
            if ((unsigned)(v >> 32) != ut) fastm = false;
        }
        if (!fastm) {
            int g = 0;
            do {
                v = __hip_atomic_load(src, __ATOMIC_RELAXED, __HIP_MEMORY_SCOPE_AGENT);
            } while ((unsigned)(v >> 32) != ut && ++g < (1 << 21));
        }
        hin[0][w * 64 + u] = __uint_as_float((unsigned)v);
    }
    __syncthreads();
    {
        const float4* hl4 = (const float4*)hloc[0];
        const float4* hn4 = (const float4*)hin[0];
        const float4* hs = (s == q) ? hl4 : (hn4 + ((s - q + 3) & 3) * 16);
        float b0 = 0.f, b1 = 0.f, b2 = 0.f, b3 = 0.f;
#pragma unroll
        for (int k = 0; k < 16; ++k) {
            float4 hh = hs[k];
            b0 += fw[k].x * hh.x;
            b1 += fw[k].y * hh.y;
            b2 += fw[k].z * hh.z;
            b3 += fw[k].w * hh.w;
        }
        float lg = (b0 + b1) + (b2 + b3);
        lg += __shfl_xor(lg, 1);
        lg += __shfl_xor(lg, 2);
        if (s == 0)
            __builtin_nontemporal_store(lg + fcb,
                out + ((size_t)(b * TT + (TT - 1)) << 8) + jg);
    }
}

// ---------------- launch ------------------------------------------------------
extern "C" void kernel_launch(void* const* d_in, const int* in_sizes, int n_in,
                              void* d_out, int out_size, void* d_ws, size_t ws_size,
                              hipStream_t stream) {
    const int*   x    = (const int*)d_in[0];
    const float* W_ih = (const float*)d_in[1];
    const float* W_hh = (const float*)d_in[2];
    const float* b_ih = (const float*)d_in[3];
    const float* b_hh = (const float*)d_in[4];
    const float* fc_W = (const float*)d_in[5];
    const float* fc_b = (const float*)d_in[6];
    float* out  = (float*)d_out;
    float* ws_f = (float*)d_ws;
    unsigned long long* hbuf = (unsigned long long*)(ws_f + HBUF_OFF);
    unsigned* xmap = (unsigned*)(ws_f + XMAP_OFF);

    k_prep<<<(WS_TOT + 255) / 256, 256, 0, stream>>>(W_ih, b_ih, b_hh, ws_f);
    k_lstm<<<256, 256, 0, stream>>>(x, W_hh, ws_f, hbuf, xmap, fc_W, fc_b, out);
}

// Round 2
// 6199.723 us; speedup vs baseline: 1.4248x; 1.4248x over previous
//
#include <hip/hip_runtime.h>
#include <stdint.h>

#define TT 2048
#define BB 64
#define HH 256

// ws float-word layout
#define WIHT_OFF 0          // W_ih^T : 256 tokens x 1024 gate-rows
#define BIAS_OFF 262144     // b_ih + b_hh : 1024
#define HBUF_OFF 263168     // packed h exchange: u64[2][64][256] = 65536 floats
#define XMAP_OFF 328704     // 256 u32: per-WG published XCC id (0x100 | id)
#define WS_TOT   328960

#define LOGITS   33554432   // 64*2048*256

// ---------------- K1: prep (transpose W_ih, fuse biases, zero exch+xmap) ------
__global__ __launch_bounds__(256, 1) void k_prep(const float* __restrict__ W_ih,
                                                 const float* __restrict__ b_ih,
                                                 const float* __restrict__ b_hh,
                                                 float* ws_f) {
    int idx = blockIdx.x * 256 + threadIdx.x;
    if (idx < 262144) {
        int v = idx >> 10, r = idx & 1023;
        ws_f[WIHT_OFF + idx] = W_ih[r * 256 + v];
    } else if (idx < 263168) {
        int r = idx - 262144;
        ws_f[idx] = b_ih[r] + b_hh[r];
    } else if (idx < WS_TOT) {
        ws_f[idx] = 0.0f;   // exchange slots (epoch=0,val=0) + xcc map = 0
    }
}

// fast activations (no ocml branches); __expf -> v_exp_f32
__device__ __forceinline__ float sigm_f(float x) { return 1.0f / (1.0f + __expf(-x)); }
__device__ __forceinline__ float tanh_f(float x) {
    float e = __expf(2.0f * x);
    return 1.0f - 2.0f / (e + 1.0f);   // +-inf-safe: -> 1 / -1
}

// fast-path read: bypass L1, served from the (shared, same-XCD) L2.
__device__ __forceinline__ unsigned long long ld_l2(const unsigned long long* p) {
    unsigned long long v;
    asm volatile("global_load_dwordx2 %0, %1, off sc0\n\ts_waitcnt vmcnt(0)"
                 : "=v"(v) : "v"(p) : "memory");
    return v;
}
// fast-path store: plain sc0 store -> lands DIRTY in the local XCD L2, which
// the sc0 poll above hits at L2 latency. Only meaningful when all 4 peers
// share an XCD (fastm); the agent-scope store that always follows carries the
// identical value, so any store ordering/visibility interleave is correct.
__device__ __forceinline__ void st_l2(unsigned long long* p, unsigned long long v) {
    asm volatile("global_store_dwordx2 %0, %1, off sc0" :: "v"(p), "v"(v) : "memory");
}

// ---------------- K2: persistent LSTM recurrence ------------------------------
// 256 WGs x 256 threads; WG (b,q) owns hidden units [q*64,q*64+64) of batch b.
// Round-0 structure, with: (1) dual-store exchange (sc0 L2-resident store on
// the critical path + agent store for the proven fallback), (2) TWO barriers
// per step: gate combine is computed REDUNDANTLY by all 4 waves (each wave has
// a private hloc copy; hin/gbuf double-buffered by parity), (3) next-step
// x_proj gather prefetched a full step ahead.
__global__ __launch_bounds__(256, 1) void k_lstm(const int* __restrict__ x,
                                                 const float* __restrict__ W_hh,
                                                 const float* __restrict__ wsro,
                                                 unsigned long long* __restrict__ hbuf,
                                                 unsigned* __restrict__ xmap,
                                                 float* __restrict__ out) {
    const int tid = threadIdx.x;
    const int bid = blockIdx.x;
    const int xcd  = bid & 7;
    const int slot = bid >> 3;
    const int b = xcd + 8 * (slot >> 2);
    const int q = slot & 3;
    const int u  = tid & 63;
    const int w  = tid >> 6;            // wave id = quarter it polls; gate id
    const int j  = q * 64 + u;
    const int r  = w * 256 + j;         // gate row in [0,1024)

    __shared__ alignas(16) float hin[2][192];   // remote quarters, rotated, dbuf
    __shared__ alignas(16) float hloc[4][64];   // PER-WAVE private copy of own h
    __shared__ float gbuf[2][256];              // gate exchange, dbuf
    __shared__ int xs[4];

    // ---- one-time: W_hh row r -> regs, column-rotated (own quarter last) ----
    float4 w4[64];
#pragma unroll
    for (int i = 0; i < 64; ++i) {
        int cb = (i < 48) ? ((q + 1 + (i >> 4)) & 3) : q;
        int wi = (i < 48) ? (i & 15) : (i - 48);
        w4[i] = *(const float4*)(W_hh + (size_t)r * 256 + cb * 64 + wi * 4);
    }
    const float bias_r = wsro[BIAS_OFF + r];
    const int* xrow = x + b * TT;
    const bool ownw = (w == q);
    const int rb = (w - q + 3) & 3;     // rotated hin slot for polled quarter

    // ---- one-time: XCC handshake (ground truth; failure -> slow mode) ----
    int myxcc = 0;
    asm volatile("s_getreg_b32 %0, hwreg(HW_REG_XCC_ID)" : "=s"(myxcc));
    if (tid == 0)
        __hip_atomic_store(&xmap[bid], 0x100u | (unsigned)myxcc,
                           __ATOMIC_RELAXED, __HIP_MEMORY_SCOPE_AGENT);
    if (tid < 4) {
        int pb = (b & 7) + 8 * ((b >> 3) * 4 + tid);
        unsigned v; int g = 0;
        do {
            v = __hip_atomic_load(&xmap[pb], __ATOMIC_RELAXED, __HIP_MEMORY_SCOPE_AGENT);
        } while (!(v & 0x100u) && ++g < (1 << 20));
        xs[tid] = (v & 0x100u) ? (int)(v & 0xffu) : -1 - tid;  // timeout -> mismatch
    }
    hloc[w][u] = 0.0f;                  // h(0) = 0, every wave's private copy
    float c_state = 0.0f;               // redundant per wave, identical values
    float hval = 0.0f;
    __syncthreads();
    bool fastm = (xs[0] == xs[1]) & (xs[1] == xs[2]) & (xs[2] == xs[3]);

    const float4* hl4 = (const float4*)hloc[w];

    // prefetch x_proj for t=0 (coalesced: 256B per wave)
    float xw_cur = wsro[WIHT_OFF + xrow[0] * 1024 + r] + bias_r;

    for (int t = 0; t < TT; ++t) {
        const int p = t & 1;
        // issue next step's gather NOW — a full step of latency cover
        const int tn = (t + 1 < TT) ? t + 1 : t;
        const float xw_next_raw = wsro[WIHT_OFF + xrow[tn] * 1024 + r];

        // own-quarter partial dot from the private hloc copy (same-wave RAW,
        // no barrier needed) — hides under the exchange latency
        float a0 = 0.f, a1 = 0.f, a2 = 0.f, a3 = 0.f;
#pragma unroll
        for (int i = 0; i < 16; ++i) {
            float4 hh = hl4[i];
            a0 += w4[48 + i].x * hh.x;
            a1 += w4[48 + i].y * hh.y;
            a2 += w4[48 + i].z * hh.z;
            a3 += w4[48 + i].w * hh.w;
        }

        // poll remote quarter (packed epoch|value), write rotated slot
        if (!ownw) {
            const unsigned long long* src = hbuf + (size_t)p * (BB * HH) + b * HH + tid;
            const unsigned ut = (unsigned)t;
            unsigned long long v = 0;
            if (fastm) {                 // shared-L2 poll, guarded
                int g = 0;
                do { v = ld_l2(src); } while ((unsigned)(v >> 32) != ut && ++g < 6000);
                if ((unsigned)(v >> 32) != ut) fastm = false;  // sticky fallback
            }
            if (!fastm) {                // proven device-scope path
                int g = 0;
                do {
                    v = __hip_atomic_load(src, __ATOMIC_RELAXED, __HIP_MEMORY_SCOPE_AGENT);
                } while ((unsigned)(v >> 32) != ut && ++g < (1 << 21));
            }
            hin[p][rb * 64 + u] = __uint_as_float((unsigned)v);
        }
        __syncthreads();                 // bar1: hin[p] ready

        // remaining 3 quarters, branch-free (rotation did the index mapping)
        const float4* hn4 = (const float4*)hin[p];
#pragma unroll
        for (int i = 0; i < 48; ++i) {
            float4 hh = hn4[i];
            a0 += w4[i].x * hh.x;
            a1 += w4[i].y * hh.y;
            a2 += w4[i].z * hh.z;
            a3 += w4[i].w * hh.w;
        }
        float gate = xw_cur + ((a0 + a1) + (a2 + a3));
        float act = (w == 2) ? tanh_f(gate) : sigm_f(gate);  // wave-uniform
        gbuf[p][tid] = act;
        __syncthreads();                 // bar2: gbuf[p] ready

        // gate combine: REDUNDANT on all 4 waves (stride-1 LDS reads,
        // conflict-free). Kills the 3rd barrier and the serial wave0 tail.
        float ig = gbuf[p][u],       fg = gbuf[p][64 + u];
        float gg = gbuf[p][128 + u], og = gbuf[p][192 + u];
        c_state = fg * c_state + ig * gg;
        hval = og * tanh_f(c_state);

        if (ownw) {                      // the non-polling wave produces
            unsigned long long pv =
                ((unsigned long long)(unsigned)(t + 1) << 32) |
                (unsigned long long)__float_as_uint(hval);
            unsigned long long* dst =
                hbuf + (size_t)((t + 1) & 1) * (BB * HH) + b * HH + j;
            if (fastm) st_l2(dst, pv);   // critical-path L2-resident store
            __hip_atomic_store(dst, pv, __ATOMIC_RELAXED, __HIP_MEMORY_SCOPE_AGENT);
            out[((size_t)(b * TT + t) << 8) + j] = hval;     // h history
        }
        hloc[w][u] = hval;               // private copy for next step's A
        xw_cur = xw_next_raw + bias_r;
    }

    if (ownw) {
        out[LOGITS + b * HH + j] = hval;                     // h_n
        out[LOGITS + BB * HH + b * HH + j] = c_state;        // c_n
    }
}

// ---------------- K3: FC epilogue, in-place over the logits region ------------
__global__ __launch_bounds__(256, 1) void k_fc(const float* __restrict__ fc_W,
                                               const float* __restrict__ fc_b,
                                               float* out) {
    __shared__ alignas(16) float ht[64][256];
    const int tid = threadIdx.x;
    const size_t base = (size_t)blockIdx.x * 64;
    for (int i = 0; i < 64; ++i)
        ht[i][tid] = out[(base + i) * 256 + tid];

    float4 w4[64];
    const float4* wr = (const float4*)(fc_W + (size_t)tid * 256);
#pragma unroll
    for (int k = 0; k < 64; ++k) w4[k] = wr[k];
    const float bias = fc_b[tid];
    __syncthreads();

    for (int m = 0; m < 64; ++m) {
        const float4* hv = (const float4*)ht[m];
        float a0 = 0.f, a1 = 0.f, a2 = 0.f, a3 = 0.f;
#pragma unroll
        for (int k = 0; k < 64; ++k) {
            float4 hh = hv[k];
            a0 += w4[k].x * hh.x;
            a1 += w4[k].y * hh.y;
            a2 += w4[k].z * hh.z;
            a3 += w4[k].w * hh.w;
        }
        out[(base + m) * 256 + tid] = bias + ((a0 + a1) + (a2 + a3));
    }
}

// ---------------- launch ------------------------------------------------------
extern "C" void kernel_launch(void* const* d_in, const int* in_sizes, int n_in,
                              void* d_out, int out_size, void* d_ws, size_t ws_size,
                              hipStream_t stream) {
    const int*   x    = (const int*)d_in[0];
    const float* W_ih = (const float*)d_in[1];
    const float* W_hh = (const float*)d_in[2];
    const float* b_ih = (const float*)d_in[3];
    const float* b_hh = (const float*)d_in[4];
    const float* fc_W = (const float*)d_in[5];
    const float* fc_b = (const float*)d_in[6];
    float* out  = (float*)d_out;
    float* ws_f = (float*)d_ws;
    unsigned long long* hbuf = (unsigned long long*)(ws_f + HBUF_OFF);
    unsigned* xmap = (unsigned*)(ws_f + XMAP_OFF);

    k_prep<<<(WS_TOT + 255) / 256, 256, 0, stream>>>(W_ih, b_ih, b_hh, ws_f);
    k_lstm<<<256, 256, 0, stream>>>(x, W_hh, ws_f, hbuf, xmap, out);
    k_fc<<<2048, 256, 0, stream>>>(fc_W, fc_b, out);
}